// Round 15
// baseline (112.364 us; speedup 1.0000x reference)
//
#include <hip/hip_runtime.h>
#include <math.h>

#pragma clang fp contract(off)

// ---------------------------------------------------------------------------
// Bit-exact fp32 emulation of the XLA-CPU (reassoc+contract) reference
// realization — PASSING since r10 (absmax 0.1875, bit-stable r10-r14).
// Per-step tree (unchanged):
//   u = fadd( fma(s3,a1, mul(s2,b2)), fma(s1,a3, -divcr(mul(s0,d4), d)) )
// r14: plain ops under contract(off) freed the scheduler (63us) but one chain
// is latency-bound (143 cyc/step vs 40 issue floor). This round: 2 problems
// per thread — r12's idea, which failed ONLY because inline asm pinned program
// order (zero overlap). With schedulable plain ops the two independent chains
// interleave and fill each other's bubbles. Per-problem op stream identical.
// ---------------------------------------------------------------------------

__device__ __forceinline__ float fmul32(float a, float b) { return a * b; }
__device__ __forceinline__ float fadd32(float a, float b) { return a + b; }
__device__ __forceinline__ float fsub32(float a, float b) { return a - b; }
#define FMA32(a, b, c) __builtin_fmaf((a), (b), (c))

constexpr double RD64  = 100.0 / 1000.0;
constexpr double RD2   = RD64 * RD64;
constexpr float  KA32  = (float)(13.0 / 15.0 * RD2);
constexpr float  KB32  = (float)( 7.0 / 60.0 * RD2);
constexpr float  KC32  = (float)( 3.0 / 40.0 * RD2);
constexpr float  nKC32 = -KC32;
constexpr float  DRD32 = (float)(12.0 * RD64);
constexpr float  ISC32 = (float)(2.0 * RD64 / 45.0);
constexpr double Q64   = (100.0 - 0.1) / 999.0;     // np.linspace step

// VCC-free correctly-rounding fp32 divide (benign range: d ~ 1, n finite).
__device__ __forceinline__ float divcr(float n, float d) {
  float y0 = __builtin_amdgcn_rcpf(d);
  float e0 = FMA32(-d, y0, 1.0f);
  float y1 = FMA32(y0, e0, y0);
  float e1 = FMA32(-d, y1, 1.0f);
  float y2 = FMA32(y1, e1, y1);
  float q0 = fmul32(n, y2);
  float r  = FMA32(-d, q0, n);
  return FMA32(r, y2, q0);
}

struct CS {                       // one chain's rolling state (VGPRs)
  float s0, s1, s2, s3;
  float a1, a2, a3, b1, b2, d1, d2, d3, d4;
  float me;
  const float2* tvl;
};

__device__ __forceinline__ void cstep(CS& c, float tx, float ty) {
  float f  = fadd32(tx, fsub32(c.me, ty));
  float ai = FMA32(KA32, f, 2.0f);
  float bi = FMA32(KB32, f, -2.0f);
  float di = FMA32(nKC32, f, 1.0f);     // d = 1 - KC*f
  float w  = divcr(fmul32(c.s0, c.d4), di);
  float m2 = fmul32(c.s2, c.b2);
  float t1 = FMA32(c.s3, c.a1, m2);
  float t2 = FMA32(c.s1, c.a3, -w);     // == fma(s1,a3, q) bitwise (c=-d)
  float u  = fadd32(t1, t2);
  c.d4 = c.d3; c.d3 = c.d2; c.d2 = c.d1; c.d1 = di;
  c.a3 = c.a2; c.a2 = c.a1; c.a1 = ai;
  c.b2 = c.b1; c.b1 = bi;
  c.s0 = c.s1; c.s1 = c.s2; c.s2 = c.s3; c.s3 = u;
}
__device__ __forceinline__ float fval(const CS& c, int idx) {
  float2 t = c.tvl[idx];
  return fadd32(t.x, fsub32(c.me, t.y));
}
__device__ __forceinline__ void seed(CS& c, float f0, float f1, float f2, float f3) {
  c.a1 = FMA32(KA32, f3, 2.0f);  c.a2 = FMA32(KA32, f2, 2.0f);  c.a3 = FMA32(KA32, f1, 2.0f);
  c.b1 = FMA32(KB32, f3, -2.0f); c.b2 = FMA32(KB32, f2, -2.0f);
  c.d1 = FMA32(nKC32, f3, 1.0f); c.d2 = FMA32(nKC32, f2, 1.0f);
  c.d3 = FMA32(nKC32, f1, 1.0f); c.d4 = FMA32(nKC32, f0, 1.0f);
}
__device__ __forceinline__ float panel(float f0, float f1, float f2, float f3, float f4) {
  float s1q = FMA32(f0, f0, fmul32(f4, f4));
  float s3q = FMA32(f1, f1, fmul32(f3, f3));
  float t   = FMA32(7.0f, s1q, fmul32(32.0f, s3q));
  float g   = FMA32(12.0f, f2, t);
  return fmul32(g, ISC32);
}
__device__ __forceinline__ float der5(float f4, float f3, float f2, float f1, float f0) {
  float m48 = fmul32(48.0f, f3);
  float d1  = FMA32(25.0f, f4, -m48);
  float d2  = FMA32(36.0f, f2, d1);
  float d3  = FMA32(-16.0f, f1, d2);
  float d4v = FMA32(3.0f, f0, d3);
  return d4v / DRD32;
}
__device__ __forceinline__ void fwd_init(CS& c, int l, const float* rr) {
  #pragma unroll
  for (int i = 0; i < 4; ++i) {           // powf ~CR via exact fp64 powers
    double rd = (double)rr[i];
    double r2 = rd * rd;
    float p1, p2;
    if (l == 0)      { p1 = rr[i];            p2 = (float)r2;        }
    else if (l == 1) { p1 = (float)r2;        p2 = (float)(r2 * rd); }
    else             { p1 = (float)(r2 * rd); p2 = (float)(r2 * r2); }
    float q  = p2 / (float)(2 * (l + 1));
    float u0 = fsub32(p1, q);
    if (i == 0) c.s0 = u0; else if (i == 1) c.s1 = u0;
    else if (i == 2) c.s2 = u0; else c.s3 = u0;
  }
  seed(c, fval(c, 0), fval(c, 1), fval(c, 2), fval(c, 3));
}
__device__ __forceinline__ void bwd_init(CS& c, int l, const float* rr, float e) {
  float sq = (float)sqrt((double)fabsf(e));
  #pragma unroll
  for (int i = 0; i < 4; ++i) {
    float x    = fmul32(rr[i], sq);
    float xl   = (l == 0) ? 1.0f : ((l == 1) ? x : fmul32(x, x));
    float fact = (l == 0) ? 1.0f : ((l == 1) ? 3.0f : 15.0f);
    float base = xl / fact;
    float h  = fmul32(x, x) / 2.0f;
    float c1 = (float)(2 * l + 3);
    float c2 = (float)(2 * (2 * l + 3) * (2 * l + 5));
    float t2 = fadd32(1.0f, h / c1);
    float series = fadd32(t2, fmul32(h, h) / c2);
    float ui = fmul32(fmul32(rr[i], base), series);
    if (i == 0) c.s0 = ui; else if (i == 1) c.s1 = ui;
    else if (i == 2) c.s2 = ui; else c.s3 = ui;
  }
  seed(c, fval(c, 999), fval(c, 998), fval(c, 997), fval(c, 996));
}

__global__ __launch_bounds__(64)
void eval_eig_kernel(const float* __restrict__ ein, float* __restrict__ out, int ntot) {
  __shared__ __align__(16) float2 tv[3][1000];   // { l(l+1)/r^2 , 1/r }
  __shared__ float gbA[224][64];                 // backward Simpson panels (A)
  __shared__ float gbB[224][64];                 // backward Simpson panels (B)

  for (int t = threadIdx.x; t < 3000; t += 64) {
    int li = t / 1000, i = t - li * 1000;
    double y = (double)i * Q64 + 0.1;
    float r  = (i == 999) ? 100.0f : (float)y;
    float r2 = fmul32(r, r);
    float num = (float)(li * (li + 1));
    tv[li][i] = make_float2(num / r2, 1.0f / r);
  }
  __syncthreads();

  const int gtid = blockIdx.x * 64 + threadIdx.x;
  const int pA = 2 * gtid;
  if (pA >= ntot) return;
  const bool hasB = (pA + 1) < ntot;
  const int pB = hasB ? (pA + 1) : pA;

  const int bA = pA / 3, lA = pA - bA * 3;
  const int bB = pB / 3, lB = pB - bB * 3;
  const float eA = ein[bA], eB = ein[bB];

  CS cA, cB;
  cA.me = -eA; cA.tvl = tv[lA];
  cB.me = -eB; cB.tvl = tv[lB];

  float rr[4];
  #pragma unroll
  for (int i = 0; i < 4; ++i) rr[i] = (float)((double)i * Q64 + 0.1);

  float lf_inA, lf_inB, integ_inA, integ_inB, u100A, u100B;

  // ====================== forward chains: u_zero, i = 4..100 =================
  {
    fwd_init(cA, lA, rr);
    fwd_init(cB, lB, rr);
    float p0A = cA.s0, p1A = cA.s1, p2A = cA.s2, p3A = cA.s3;
    float p0B = cB.s0, p1B = cB.s1, p2B = cB.s2, p3B = cB.s3;
    { float2 t = cA.tvl[4]; cstep(cA, t.x, t.y); }
    { float2 t = cB.tvl[4]; cstep(cB, t.x, t.y); }
    float accIA = panel(p0A, p1A, p2A, p3A, cA.s3); float pbA = cA.s3;
    float accIB = panel(p0B, p1B, p2B, p3B, cB.s3); float pbB = cB.s3;
    #pragma unroll 2
    for (int k = 1; k < 24; ++k) {
      int base = 4 * k;
      float q1A, q2A, q3A, q4A, q1B, q2B, q3B, q4B;
      { float2 t = cA.tvl[base + 1]; cstep(cA, t.x, t.y); q1A = cA.s3; }
      { float2 t = cB.tvl[base + 1]; cstep(cB, t.x, t.y); q1B = cB.s3; }
      { float2 t = cA.tvl[base + 2]; cstep(cA, t.x, t.y); q2A = cA.s3; }
      { float2 t = cB.tvl[base + 2]; cstep(cB, t.x, t.y); q2B = cB.s3; }
      { float2 t = cA.tvl[base + 3]; cstep(cA, t.x, t.y); q3A = cA.s3; }
      { float2 t = cB.tvl[base + 3]; cstep(cB, t.x, t.y); q3B = cB.s3; }
      { float2 t = cA.tvl[base + 4]; cstep(cA, t.x, t.y); q4A = cA.s3; }
      { float2 t = cB.tvl[base + 4]; cstep(cB, t.x, t.y); q4B = cB.s3; }
      accIA = fadd32(accIA, panel(pbA, q1A, q2A, q3A, q4A)); pbA = q4A;
      accIB = fadd32(accIB, panel(pbB, q1B, q2B, q3B, q4B)); pbB = q4B;
    }
    float u96A = pbA, u96B = pbB, u97A, u97B, u98A, u98B, u99A, u99B;
    { float2 t = cA.tvl[97]; cstep(cA, t.x, t.y); u97A = cA.s3; }
    { float2 t = cB.tvl[97]; cstep(cB, t.x, t.y); u97B = cB.s3; }
    { float2 t = cA.tvl[98]; cstep(cA, t.x, t.y); u98A = cA.s3; }
    { float2 t = cB.tvl[98]; cstep(cB, t.x, t.y); u98B = cB.s3; }
    { float2 t = cA.tvl[99]; cstep(cA, t.x, t.y); u99A = cA.s3; }
    { float2 t = cB.tvl[99]; cstep(cB, t.x, t.y); u99B = cB.s3; }
    { float2 t = cA.tvl[100]; cstep(cA, t.x, t.y); u100A = cA.s3; }
    { float2 t = cB.tvl[100]; cstep(cB, t.x, t.y); u100B = cB.s3; }
    integ_inA = accIA; integ_inB = accIB;
    lf_inA = der5(u100A, u99A, u98A, u97A, u96A) / u100A;
    lf_inB = der5(u100B, u99B, u98B, u97B, u96B) / u100B;
  }

  // =============== backward chains: v[j], j=4..999, factor idx 999-j =========
  float lf_outA, lf_outB, integ_outA, integ_outB, v899A, v899B;
  {
    bwd_init(cA, lA, rr, eA);
    bwd_init(cB, lB, rr, eB);

    // Segment A: m = 995..896 (25 groups of 4, descending within group)
    #pragma unroll 2
    for (int g = 0; g < 25; ++g) {
      int m0 = 992 - 4 * g;
      float4 la = *(const float4*)&cA.tvl[m0], ha = *(const float4*)&cA.tvl[m0 + 2];
      float4 lb = *(const float4*)&cB.tvl[m0], hb = *(const float4*)&cB.tvl[m0 + 2];
      cstep(cA, ha.z, ha.w); cstep(cB, hb.z, hb.w);
      cstep(cA, ha.x, ha.y); cstep(cB, hb.x, hb.y);
      cstep(cA, la.z, la.w); cstep(cB, lb.z, lb.w);
      cstep(cA, la.x, la.y); cstep(cB, lb.x, lb.y);
    }
    float r4A = cA.s3, r4B = cB.s3;       // u[896] opens panel 223

    float v900A, v901A, v902A, v903A, v900B, v901B, v902B, v903B;
    // Panel group: steps m=4P+3..4P for both chains, close panel P.
    #define BG2(P)                                                             \
      float4 la = *(const float4*)&cA.tvl[4 * (P)];                            \
      float4 ha = *(const float4*)&cA.tvl[4 * (P) + 2];                        \
      float4 lb = *(const float4*)&cB.tvl[4 * (P)];                            \
      float4 hb = *(const float4*)&cB.tvl[4 * (P) + 2];                        \
      cstep(cA, ha.z, ha.w); cstep(cB, hb.z, hb.w);                            \
      float f3A = cA.s3, f3B = cB.s3;                                          \
      cstep(cA, ha.x, ha.y); cstep(cB, hb.x, hb.y);                            \
      float f2A = cA.s3, f2B = cB.s3;                                          \
      cstep(cA, la.z, la.w); cstep(cB, lb.z, lb.w);                            \
      float f1A = cA.s3, f1B = cB.s3;                                          \
      cstep(cA, la.x, la.y); cstep(cB, lb.x, lb.y);                            \
      float f0A = cA.s3, f0B = cB.s3;                                          \
      gbA[(P)][threadIdx.x] = panel(f0A, f1A, f2A, f3A, r4A);                  \
      gbB[(P)][threadIdx.x] = panel(f0B, f1B, f2B, f3B, r4B);                  \
      r4A = f0A; r4B = f0B;

    // Segment B1: panels 223..26
    #pragma unroll 2
    for (int p = 223; p >= 26; --p) { BG2(p); }
    // Panel 25: f0 = u[100] = u_infty[MR]
    { BG2(25); v899A = f0A; v899B = f0B; }
    // Panel 24: f3..f0 = u[99], u[98], u[97], u[96]
    { BG2(24);
      v900A = f3A; v901A = f2A; v902A = f1A; v903A = f0A;
      v900B = f3B; v901B = f2B; v902B = f1B; v903B = f0B; }
    // Segment B2: panels 23..0
    #pragma unroll 2
    for (int p = 23; p >= 0; --p) { BG2(p); }
    #undef BG2

    // numpy .sum(0): sequential ascending panel order
    float aA = gbA[0][threadIdx.x], aB = gbB[0][threadIdx.x];
    for (int p = 1; p < 224; ++p) {
      aA = fadd32(aA, gbA[p][threadIdx.x]);
      aB = fadd32(aB, gbB[p][threadIdx.x]);
    }
    integ_outA = aA; integ_outB = aB;
    lf_outA = der5(v899A, v900A, v901A, v902A, v903A) / v899A;
    lf_outB = der5(v899B, v900B, v901B, v902B, v903B) / v899B;
  }

  // ======= final combine, fp32 in reference order =======
  {
    float uzsq = fmul32(u100A, u100A);
    float uisq = fmul32(v899A, v899A);
    float den  = fadd32(integ_inA / uzsq, integ_outA / uisq);
    float dnum = fsub32(lf_outA, lf_inA);
    float delta = (-dnum) / den;
    out[pA] = fadd32(eA, delta);
  }
  if (hasB) {
    float uzsq = fmul32(u100B, u100B);
    float uisq = fmul32(v899B, v899B);
    float den  = fadd32(integ_inB / uzsq, integ_outB / uisq);
    float dnum = fsub32(lf_outB, lf_inB);
    float delta = (-dnum) / den;
    out[pB] = fadd32(eB, delta);
  }
}

extern "C" void kernel_launch(void* const* d_in, const int* in_sizes, int n_in,
                              void* d_out, int out_size, void* d_ws, size_t ws_size,
                              hipStream_t stream) {
  const float* ein = (const float*)d_in[0];
  float* out = (float*)d_out;
  int ntot = in_sizes[0] * 3;                   // 4096 energies x 3 l-values
  int nthread = (ntot + 1) / 2;                 // 2 problems per thread
  int grid = (nthread + 63) / 64;               // 96 blocks
  eval_eig_kernel<<<dim3(grid), dim3(64), 0, stream>>>(ein, out, ntot);
}

// Round 16
// 62.744 us; speedup vs baseline: 1.7908x; 1.7908x over previous
//
#include <hip/hip_runtime.h>
#include <math.h>

#pragma clang fp contract(off)

// ---------------------------------------------------------------------------
// Bit-exact fp32 emulation of the XLA-CPU (reassoc+contract) reference
// realization — PASSING since r10 (absmax 0.1875, bit-stable r10-r15).
// Per-step value tree (unchanged since r10):
//   u = fadd( fma(s3,a1, mul(s2,b2)), fma(s1,a3, -w) ),
//   w = Markstein(n=mul(s0,d4), d, y2),  y2 = rcp+2xNewton(d)  [VCC-free CR]
// r15 lesson: pairing two problems per thread serializes (register-pressure
// scheduler; VGPR stayed 132). This round keeps r14's 1-problem structure and
// restructures WITHIN the chain: the reciprocal refinement y2(d) depends only
// on the table, so all 4 table phases of a group (f,a,b,d,y2 — independent
// ILP) are hoisted ahead of the 4 chain phases (short dependence chain with
// 4-step slack on the divide numerator). Identical instructions & operands,
// earlier schedule => identical bits. Explicit next-group float4 prefetch.
// ---------------------------------------------------------------------------

__device__ __forceinline__ float fmul32(float a, float b) { return a * b; }
__device__ __forceinline__ float fadd32(float a, float b) { return a + b; }
__device__ __forceinline__ float fsub32(float a, float b) { return a - b; }
#define FMA32(a, b, c) __builtin_fmaf((a), (b), (c))

__global__ __launch_bounds__(64)
void eval_eig_kernel(const float* __restrict__ ein, float* __restrict__ out, int ntot) {
  constexpr double RD64  = 100.0 / 1000.0;
  constexpr double RD2   = RD64 * RD64;
  constexpr float  KA32  = (float)(13.0 / 15.0 * RD2);
  constexpr float  KB32  = (float)( 7.0 / 60.0 * RD2);
  constexpr float  KC32  = (float)( 3.0 / 40.0 * RD2);
  constexpr float  nKC32 = -KC32;
  constexpr float  DRD32 = (float)(12.0 * RD64);
  constexpr float  ISC32 = (float)(2.0 * RD64 / 45.0);
  constexpr double Q64   = (100.0 - 0.1) / 999.0;     // np.linspace step

  __shared__ __align__(16) float2 tv[3][1000];   // { l(l+1)/r^2 , 1/r }
  __shared__ float gbuf[224][64];                // backward Simpson panels

  for (int t = threadIdx.x; t < 3000; t += 64) {
    int li = t / 1000, i = t - li * 1000;
    double y = (double)i * Q64 + 0.1;
    float r  = (i == 999) ? 100.0f : (float)y;
    float r2 = fmul32(r, r);
    float num = (float)(li * (li + 1));
    tv[li][i] = make_float2(num / r2, 1.0f / r);
  }
  __syncthreads();

  const int tid = blockIdx.x * 64 + threadIdx.x;
  if (tid >= ntot) return;
  const int b = tid / 3;
  const int l = tid - b * 3;
  const float e  = ein[b];
  const float me = -e;
  const float2* __restrict__ tvl = tv[l];

  // ---- table phase: coefficients + VCC-free reciprocal refinement --------
  struct Coef { float a, bc, d, y2; };
  auto MKC = [&](float tx, float ty) -> Coef {
    Coef c;
    float f  = fadd32(tx, fsub32(me, ty));
    c.a  = FMA32(KA32, f, 2.0f);
    c.bc = FMA32(KB32, f, -2.0f);
    c.d  = FMA32(nKC32, f, 1.0f);          // d = 1 - KC*f
    float y0 = __builtin_amdgcn_rcpf(c.d);
    float e0 = FMA32(-c.d, y0, 1.0f);
    float y1 = FMA32(y0, e0, y0);
    float e1 = FMA32(-c.d, y1, 1.0f);
    c.y2 = FMA32(y1, e1, y1);
    return c;
  };

  // ---- chain state + chain phase (same value tree as r10-r15) ------------
  float s0, s1, s2, s3;
  float a_m1, a_m2, a_m3, b_m1, b_m2, d_m1, d_m2, d_m3, d_m4;
  auto CSTEP = [&](const Coef& c) {
    float n  = fmul32(s0, d_m4);
    float q0 = fmul32(n, c.y2);
    float r  = FMA32(-c.d, q0, n);
    float w  = FMA32(r, c.y2, q0);         // == divcr(n, d) bitwise
    float m2 = fmul32(s2, b_m2);
    float t1 = FMA32(s3, a_m1, m2);
    float t2 = FMA32(s1, a_m3, -w);        // == fma(s1,a3, q) bitwise (c=-d)
    float u  = fadd32(t1, t2);
    d_m4 = d_m3; d_m3 = d_m2; d_m2 = d_m1; d_m1 = c.d;
    a_m3 = a_m2; a_m2 = a_m1; a_m1 = c.a;
    b_m2 = b_m1; b_m1 = c.bc;
    s0 = s1; s1 = s2; s2 = s3; s3 = u;
  };

  auto FVAL = [&](int idx) -> float {
    float2 t_ = tvl[idx];
    return fadd32(t_.x, fsub32(me, t_.y));
  };
  auto SEED = [&](float f0, float f1, float f2v, float f3) {
    a_m1 = FMA32(KA32, f3, 2.0f);
    a_m2 = FMA32(KA32, f2v, 2.0f);
    a_m3 = FMA32(KA32, f1, 2.0f);
    b_m1 = FMA32(KB32, f3, -2.0f);
    b_m2 = FMA32(KB32, f2v, -2.0f);
    d_m1 = FMA32(nKC32, f3, 1.0f);
    d_m2 = FMA32(nKC32, f2v, 1.0f);
    d_m3 = FMA32(nKC32, f1, 1.0f);
    d_m4 = FMA32(nKC32, f0, 1.0f);
  };
  auto PANEL = [&](float f0, float f1, float f2v, float f3, float f4) -> float {
    float s1q = FMA32(f0, f0, fmul32(f4, f4));
    float s3q = FMA32(f1, f1, fmul32(f3, f3));
    float t   = FMA32(7.0f, s1q, fmul32(32.0f, s3q));
    float g   = FMA32(12.0f, f2v, t);
    return fmul32(g, ISC32);
  };
  auto DER5 = [&](float f4, float f3, float f2v, float f1, float f0) -> float {
    float m48 = fmul32(48.0f, f3);
    float d1  = FMA32(25.0f, f4, -m48);
    float d2  = FMA32(36.0f, f2v, d1);
    float d3  = FMA32(-16.0f, f1, d2);
    float d4v = FMA32(3.0f, f0, d3);
    return d4v / DRD32;
  };

  float rr[4];
  #pragma unroll
  for (int i = 0; i < 4; ++i) rr[i] = (float)((double)i * Q64 + 0.1);

  float lf_in, lf_out, integ_in, integ_out, u100v, v899;

  // ====================== forward chain: u_zero, i = 4..100 ==================
  {
    #pragma unroll
    for (int i = 0; i < 4; ++i) {             // powf ~CR via exact fp64 powers
      double rd = (double)rr[i];
      double r2 = rd * rd;
      float p1, p2;
      if (l == 0)      { p1 = rr[i];            p2 = (float)r2;        }
      else if (l == 1) { p1 = (float)r2;        p2 = (float)(r2 * rd); }
      else             { p1 = (float)(r2 * rd); p2 = (float)(r2 * r2); }
      float q  = p2 / (float)(2 * (l + 1));
      float u0 = fsub32(p1, q);
      if (i == 0) s0 = u0; else if (i == 1) s1 = u0; else if (i == 2) s2 = u0; else s3 = u0;
    }
    SEED(FVAL(0), FVAL(1), FVAL(2), FVAL(3));

    float p0 = s0, p1 = s1, p2 = s2, p3 = s3;
    { float2 t4 = tvl[4]; Coef c = MKC(t4.x, t4.y); CSTEP(c); }
    float accI = PANEL(p0, p1, p2, p3, s3);   // panel 0; sequential .sum(0)
    float pb = s3;
    #pragma unroll 2
    for (int k = 1; k < 24; ++k) {
      int base = 4 * k;
      float2 t1v = tvl[base + 1], t2v = tvl[base + 2];
      float2 t3v = tvl[base + 3], t4v = tvl[base + 4];
      Coef c1 = MKC(t1v.x, t1v.y), c2 = MKC(t2v.x, t2v.y);
      Coef c3 = MKC(t3v.x, t3v.y), c4 = MKC(t4v.x, t4v.y);
      CSTEP(c1); float q1 = s3;
      CSTEP(c2); float q2 = s3;
      CSTEP(c3); float q3 = s3;
      CSTEP(c4); float q4 = s3;
      accI = fadd32(accI, PANEL(pb, q1, q2, q3, q4));
      pb = q4;
    }
    float u96 = pb;
    float2 t97 = tvl[97], t98 = tvl[98], t99 = tvl[99], t100 = tvl[100];
    Coef c97 = MKC(t97.x, t97.y), c98 = MKC(t98.x, t98.y);
    Coef c99 = MKC(t99.x, t99.y), c100 = MKC(t100.x, t100.y);
    CSTEP(c97);  float u97 = s3;
    CSTEP(c98);  float u98 = s3;
    CSTEP(c99);  float u99 = s3;
    CSTEP(c100); u100v = s3;
    integ_in = accI;
    lf_in = DER5(u100v, u99, u98, u97, u96) / u100v;
  }

  // =============== backward chain: v[j], j=4..999, factor idx 999-j ==========
  // u_infty index m = 999-j runs 995..0. Branch-free 4-step groups.
  {
    float sq = (float)sqrt((double)fabsf(e));
    #pragma unroll
    for (int i = 0; i < 4; ++i) {
      float x    = fmul32(rr[i], sq);
      float xl   = (l == 0) ? 1.0f : ((l == 1) ? x : fmul32(x, x));
      float fact = (l == 0) ? 1.0f : ((l == 1) ? 3.0f : 15.0f);
      float base = xl / fact;
      float h  = fmul32(x, x) / 2.0f;
      float c1 = (float)(2 * l + 3);
      float c2 = (float)(2 * (2 * l + 3) * (2 * l + 5));
      float t2 = fadd32(1.0f, h / c1);
      float series = fadd32(t2, fmul32(h, h) / c2);
      float ui = fmul32(fmul32(rr[i], base), series);
      if (i == 0) s0 = ui; else if (i == 1) s1 = ui; else if (i == 2) s2 = ui; else s3 = ui;
    }
    SEED(FVAL(999), FVAL(998), FVAL(997), FVAL(996));

    // Segment A: m = 995..896 (25 groups of 4, descending within group).
    float4 lo = *(const float4*)&tvl[992];
    float4 hi = *(const float4*)&tvl[994];
    #pragma unroll 2
    for (int g = 0; g < 25; ++g) {
      Coef c3 = MKC(hi.z, hi.w), c2 = MKC(hi.x, hi.y);
      Coef c1 = MKC(lo.z, lo.w), c0 = MKC(lo.x, lo.y);
      if (g < 24) {                         // prefetch next group
        int m0 = 992 - 4 * (g + 1);
        lo = *(const float4*)&tvl[m0];
        hi = *(const float4*)&tvl[m0 + 2];
      }
      CSTEP(c3); CSTEP(c2); CSTEP(c1); CSTEP(c0);
    }
    float r4v = s3;                         // u[896] opens panel 223

    float v900, v901, v902, v903;
    lo = *(const float4*)&tvl[4 * 223];
    hi = *(const float4*)&tvl[4 * 223 + 2];
    // Panel group macro: steps m=4p+3..4p, close panel p, hand f0 to next.
    #define BGROUP(P)                                                          \
      Coef c3 = MKC(hi.z, hi.w), c2 = MKC(hi.x, hi.y);                         \
      Coef c1 = MKC(lo.z, lo.w), c0 = MKC(lo.x, lo.y);                         \
      if ((P) > 0) {                                                           \
        lo = *(const float4*)&tvl[4 * (P) - 4];                                \
        hi = *(const float4*)&tvl[4 * (P) - 2];                                \
      }                                                                        \
      CSTEP(c3); float f3v = s3;                                               \
      CSTEP(c2); float f2w = s3;                                               \
      CSTEP(c1); float f1v = s3;                                               \
      CSTEP(c0); float f0v = s3;                                               \
      gbuf[(P)][threadIdx.x] = PANEL(f0v, f1v, f2w, f3v, r4v);                 \
      r4v = f0v;

    // Segment B1: panels 223..26
    #pragma unroll 2
    for (int p = 223; p >= 26; --p) { BGROUP(p); }
    // Panel 25: f0 = u[100] = u_infty[MR]
    { BGROUP(25); v899 = f0v; }
    // Panel 24: f3..f0 = u[99], u[98], u[97], u[96]
    { BGROUP(24); v900 = f3v; v901 = f2w; v902 = f1v; v903 = f0v; }
    // Segment B2: panels 23..0
    #pragma unroll 2
    for (int p = 23; p >= 0; --p) { BGROUP(p); }
    #undef BGROUP

    // numpy .sum(0): sequential ascending panel order
    float accO = gbuf[0][threadIdx.x];
    for (int p = 1; p < 224; ++p) accO = fadd32(accO, gbuf[p][threadIdx.x]);
    integ_out = accO;
    lf_out = DER5(v899, v900, v901, v902, v903) / v899;
  }

  // ======= final combine, fp32 in reference order =======
  float uzsq = fmul32(u100v, u100v);
  float uisq = fmul32(v899, v899);
  float den  = fadd32(integ_in / uzsq, integ_out / uisq);
  float dnum = fsub32(lf_out, lf_in);
  float delta = (-dnum) / den;
  out[tid] = fadd32(e, delta);
}

extern "C" void kernel_launch(void* const* d_in, const int* in_sizes, int n_in,
                              void* d_out, int out_size, void* d_ws, size_t ws_size,
                              hipStream_t stream) {
  const float* ein = (const float*)d_in[0];
  float* out = (float*)d_out;
  int ntot = in_sizes[0] * 3;             // 4096 energies x 3 l-values
  int grid = (ntot + 63) / 64;            // 192 blocks, 1 problem/thread
  eval_eig_kernel<<<dim3(grid), dim3(64), 0, stream>>>(ein, out, ntot);
}